// Round 20
// baseline (168.565 us; speedup 1.0000x reference)
//
#include <hip/hip_runtime.h>
#include <math.h>

// Problem constants: x(256,8192) b,q,e(8192) M(100,8192) out(256,100)
#define NN 8192
#define BB 256
#define CC 100
#define MAX_ITERS 4096

// ---------------------------------------------------------------------------
// Fire kernel: wave = one column x 64 rows (lane = row). Slim body:
//   map: cmp + mul + sub + mul + cndmask            (5 VALU)
//   band: v_med3 + cmp-neq                          (2 VALU)
//   count: a &= outside; kk += a                    (~1-2)
// No cycle detection: provably bit-exact vs the Brent fast-forward version
// (survivors of a repeating trajectory stay out-of-band -> a stays true ->
// kk counts every remaining iter -> 1 + 4096 = 4097, identical to the
// credited value and to the reference cap). Columns that cycle simply run
// to MAX_ITERS, concurrent with the bulk.
// Locked reference flavor (r10): hoisted IEEE f32 reciprocals rb=1.0f/b,
// rob=1.0f/(1-b); m' = (m<b ? m*rb : (1-m)*rob); lo=x-e, hi=x+e exact subs.
// med3(m,lo,hi) != m  <=>  (m < lo) || (m > hi)  (lo <= hi always; edge
// m==lo/hi -> in-band, matching the reference's strict compares).
// ---------------------------------------------------------------------------
__global__ __launch_bounds__(256) void fire_kernel(
    const float* __restrict__ x, const float* __restrict__ bmap,
    const float* __restrict__ qini, const float* __restrict__ eps,
    float* __restrict__ kout)
{
    const int j    = blockIdx.x;              // column (one per block)
    const int lane = threadIdx.x & 63;
    const int row  = (threadIdx.x & ~63) + lane;   // wave w covers rows 64w..64w+63

    const float bv  = bmap[j];
    const float qv  = qini[j];
    const float ev  = eps[j];
    const float obv = 1.0f - bv;              // exact (Sterbenz)
    const float rb  = 1.0f / bv;              // hoisted IEEE f32 reciprocals
    const float rob = 1.0f / obv;

    const float xv  = x[(size_t)row * NN + j];
    const float lov = xv - ev;                // exact f32 subs, same bits as ref
    const float hiv = xv + ev;

    float m  = qv;
    float kk = 1.0f;
    bool  a  = (qv != 0.0f);                  // q==0: never fires

    int it = 0;
    while (it < MAX_ITERS) {
        #pragma unroll
        for (int u = 0; u < 8; ++u) {
            const bool  lt = (m < bv);
            const float pa = m * rb;
            const float pb = (1.0f - m) * rob;
            m = lt ? pa : pb;                 // reference flavor
            const bool o = (__builtin_amdgcn_fmed3f(m, lov, hiv) != m);
            a = a && o;
            kk += a ? 1.0f : 0.0f;
        }
        it += 8;
        if (__ballot(a) == 0ull) break;       // all 64 rows fired
    }

    kout[(size_t)row * NN + j] = kk;
}

// ---------------------------------------------------------------------------
// Fused logits GEMM + norms: block = 8 rows x 5 classes, grid 640.
// Per-thread 40 f32 dot accumulators + 8 f64 k-sumsq + 5 f64 M-sumsq,
// all in the SAME j-pattern (jj = s*1024 + tid*4), same += expression,
// same shuffle ladder, same 4-wave combine as the proven r14/r18 norm
// kernel -> norms bit-identical; dot path identical to r18's logits_gemm.
// ---------------------------------------------------------------------------
#define TR 8
#define TC 5
__global__ __launch_bounds__(256) void logits_gemm(
    const float* __restrict__ k, const float* __restrict__ M,
    float* __restrict__ out)
{
    __shared__ float  red[4][TR][TC];
    __shared__ double redk[4][TR];
    __shared__ double redm[4][TC];

    const int rt  = blockIdx.x / (CC / TC);   // 0..31 row tile
    const int ct  = blockIdx.x % (CC / TC);   // 0..19 class tile
    const int r0  = rt * TR, c0 = ct * TC;
    const int tid = threadIdx.x;
    const int wid = tid >> 6, lane = tid & 63;

    float  acc[TR][TC];
    double ksq[TR];
    double msq[TC];
    #pragma unroll
    for (int r = 0; r < TR; ++r) {
        ksq[r] = 0.0;
        #pragma unroll
        for (int c = 0; c < TC; ++c) acc[r][c] = 0.0f;
    }
    #pragma unroll
    for (int c = 0; c < TC; ++c) msq[c] = 0.0;

    for (int s = 0; s < 8; ++s) {
        const int jj = s * 1024 + tid * 4;
        float4 mv[TC];
        #pragma unroll
        for (int c = 0; c < TC; ++c) {
            mv[c] = *(const float4*)(M + (size_t)(c0 + c) * NN + jj);
            msq[c] += (double)mv[c].x * mv[c].x + (double)mv[c].y * mv[c].y
                    + (double)mv[c].z * mv[c].z + (double)mv[c].w * mv[c].w;
        }
        #pragma unroll
        for (int r = 0; r < TR; ++r) {
            const float4 kv = *(const float4*)(k + (size_t)(r0 + r) * NN + jj);
            ksq[r] += (double)kv.x * kv.x + (double)kv.y * kv.y
                    + (double)kv.z * kv.z + (double)kv.w * kv.w;
            #pragma unroll
            for (int c = 0; c < TC; ++c)
                acc[r][c] += kv.x * mv[c].x + kv.y * mv[c].y
                           + kv.z * mv[c].z + kv.w * mv[c].w;
        }
    }

    #pragma unroll
    for (int off = 32; off; off >>= 1) {
        #pragma unroll
        for (int r = 0; r < TR; ++r) {
            ksq[r] += __shfl_down(ksq[r], off, 64);
            #pragma unroll
            for (int c = 0; c < TC; ++c)
                acc[r][c] += __shfl_down(acc[r][c], off, 64);
        }
        #pragma unroll
        for (int c = 0; c < TC; ++c) msq[c] += __shfl_down(msq[c], off, 64);
    }
    if (lane == 0) {
        #pragma unroll
        for (int r = 0; r < TR; ++r) {
            redk[wid][r] = ksq[r];
            #pragma unroll
            for (int c = 0; c < TC; ++c) red[wid][r][c] = acc[r][c];
        }
        #pragma unroll
        for (int c = 0; c < TC; ++c) redm[wid][c] = msq[c];
    }
    __syncthreads();

    if (tid < TR * TC) {
        const int r = tid / TC, c = tid % TC;
        const float d  = red[0][r][c] + red[1][r][c] + red[2][r][c] + red[3][r][c];
        const float kn = fmaxf((float)sqrt(redk[0][r] + redk[1][r] + redk[2][r] + redk[3][r]), 1e-8f);
        const float mn = fmaxf((float)sqrt(redm[0][c] + redm[1][c] + redm[2][c] + redm[3][c]), 1e-8f);
        out[(size_t)(r0 + r) * CC + (c0 + c)] = d / (kn * mn);
    }
}

// ===========================================================================
// FALLBACK: round-10 fused kernel, verbatim (proven green), used only if
// ws_size is too small for the k matrix.
// ===========================================================================
__global__ __launch_bounds__(256) void gls_fused_kernel(
    const float* __restrict__ x, const float* __restrict__ bmap,
    const float* __restrict__ qini, const float* __restrict__ eps,
    const float* __restrict__ M, float* __restrict__ out)
{
    __shared__ float k_lds[NN];
    __shared__ double redsh[4];

    const int i   = blockIdx.x;
    const int tid = threadIdx.x;
    const int wid = tid >> 6, lane = tid & 63;

    double sumsq = 0.0;
    for (int s = 0; s < 32; ++s) {
        const int j = tid + 256 * s;
        const float bv = bmap[j];
        const float qv = qini[j];
        const float ev = eps[j];
        const float xv = x[(size_t)i * NN + j];
        const float lov = xv - ev;
        const float hiv = xv + ev;
        const float obv = 1.0f - bv;
        const float rb  = 1.0f / bv;
        const float rob = 1.0f / obv;

        float m  = qv;
        float kk = 1.0f;
        bool  a  = (qv != 0.0f);
        for (int it = 0; a && it < MAX_ITERS; ++it) {
            const bool  lt  = (m < bv);
            const float num = lt ? m  : (1.0f - m);
            const float r   = lt ? rb : rob;
            m = num * r;
            a = (m < lov) || (m > hiv);
            kk += a ? 1.0f : 0.0f;
        }
        k_lds[j] = kk;
        sumsq += (double)kk * (double)kk;
    }

    #pragma unroll
    for (int off = 32; off; off >>= 1) sumsq += __shfl_down(sumsq, off, 64);
    if (lane == 0) redsh[wid] = sumsq;
    __syncthreads();
    const double rn = fmax(sqrt(redsh[0] + redsh[1] + redsh[2] + redsh[3]), 1e-8);

    for (int cc2 = 0; cc2 < 25; ++cc2) {
        const int c = wid * 25 + cc2;
        const float4* Mp = (const float4*)(M + (size_t)c * NN);
        double dot = 0.0, msq = 0.0;
        #pragma unroll 4
        for (int s = 0; s < 32; ++s) {
            const float4 mv = Mp[lane + 64 * s];
            const float4 kv = *(const float4*)(&k_lds[4 * (lane + 64 * s)]);
            dot += (double)kv.x * (double)mv.x + (double)kv.y * (double)mv.y
                 + (double)kv.z * (double)mv.z + (double)kv.w * (double)mv.w;
            msq += (double)mv.x * (double)mv.x + (double)mv.y * (double)mv.y
                 + (double)mv.z * (double)mv.z + (double)mv.w * (double)mv.w;
        }
        #pragma unroll
        for (int off = 32; off; off >>= 1) {
            dot += __shfl_down(dot, off, 64);
            msq += __shfl_down(msq, off, 64);
        }
        if (lane == 0) {
            const double mn = fmax(sqrt(msq), 1e-8);
            out[(size_t)i * CC + c] = (float)(dot / (rn * mn));
        }
    }
}

// ---------------------------------------------------------------------------
extern "C" void kernel_launch(void* const* d_in, const int* in_sizes, int n_in,
                              void* d_out, int out_size, void* d_ws, size_t ws_size,
                              hipStream_t stream) {
    const float* x = (const float*)d_in[0];  // (256, 8192)
    const float* b = (const float*)d_in[1];  // (8192,)
    const float* q = (const float*)d_in[2];  // (8192,)
    const float* e = (const float*)d_in[3];  // (8192,)
    const float* M = (const float*)d_in[4];  // (100, 8192)
    float* out = (float*)d_out;              // (256, 100)

    const size_t need = (size_t)BB * NN * sizeof(float);   // k matrix only
    if (ws_size >= need) {
        float* kbuf = (float*)d_ws;
        fire_kernel<<<dim3(NN), dim3(256), 0, stream>>>(x, b, q, e, kbuf);
        logits_gemm<<<dim3((BB / TR) * (CC / TC)), dim3(256), 0, stream>>>(kbuf, M, out);
    } else {
        gls_fused_kernel<<<dim3(BB), dim3(256), 0, stream>>>(x, b, q, e, M, out);
    }
}

// Round 21
// 96.385 us; speedup vs baseline: 1.7489x; 1.7489x over previous
//
#include <hip/hip_runtime.h>
#include <math.h>

// Problem constants: x(256,8192) b,q,e(8192) M(100,8192) out(256,100)
#define NN 8192
#define BB 256
#define CC 100
#define MAX_ITERS 4096

// ---------------------------------------------------------------------------
// Fire kernel: wave = one column x 64 rows (lane = row). r15 structure with
// Brent cycle detection RESTORED (r20 proved it was doing real work: the
// heavy-tail columns are cycling columns; without it they run 4096 iters and
// cost +57 us) plus two safe slimmings:
//   - band check via v_med3: med3(m,lo,hi) != m  <=>  (m<lo)||(m>hi)
//     (lo<=hi always; edges m==lo/hi in-band, matching ref's strict cmps;
//      m=+/-inf -> outside; no NaN sources on these inputs)
//   - unroll-8 window: ballot + cycle-exit once per 8 iters (post-fire iters
//     add 0 since a is false; credit at window end is exact, see below)
// Cycle fast-forward (bit-exact, detection-time-independent): when the
// wave-uniform trajectory repeats a previously-survived value, surviving
// lanes can never fire; counting every remaining iter gives kk + (4096-it),
// identical to plain iteration to the cap (1 + 4096 = 4097 = ref cap).
// Locked reference flavor (r10): hoisted IEEE f32 reciprocals rb=1.0f/b,
// rob=1.0f/(1-b); m' = (m<b ? m*rb : (1-m)*rob); lo=x-e, hi=x+e exact subs.
// ---------------------------------------------------------------------------
__global__ __launch_bounds__(256) void fire_kernel(
    const float* __restrict__ x, const float* __restrict__ bmap,
    const float* __restrict__ qini, const float* __restrict__ eps,
    float* __restrict__ kout)
{
    const int j    = blockIdx.x;              // column (one per block)
    const int lane = threadIdx.x & 63;
    const int row  = (threadIdx.x & ~63) + lane;   // wave w covers rows 64w..64w+63

    const float bv  = bmap[j];                // uniform across the wave
    const float qv  = qini[j];
    const float ev  = eps[j];
    const float obv = 1.0f - bv;              // exact (Sterbenz)
    const float rb  = 1.0f / bv;              // hoisted IEEE f32 reciprocals
    const float rob = 1.0f / obv;

    const float xv  = x[(size_t)row * NN + j];
    const float lov = xv - ev;                // exact f32 subs, same bits as ref
    const float hiv = xv + ev;

    float m = qv, anchor = qv;                // uniform trajectory state
    int   window = 1, steps = 0;
    float kk = 1.0f;
    bool  a  = (qv != 0.0f);                  // q==0: never fires
    bool  cycseen = false;

    int it = 0;
    while (it < MAX_ITERS) {
        #pragma unroll
        for (int u = 0; u < 8; ++u) {
            const bool  lt = (m < bv);
            const float pa = m * rb;
            const float pb = (1.0f - m) * rob;
            m = lt ? pa : pb;                 // reference flavor

            cycseen = cycseen || (m == anchor);   // Brent probe
            if (++steps == window) { anchor = m; window <<= 1; steps = 0; }

            const bool o = (__builtin_amdgcn_fmed3f(m, lov, hiv) != m);
            a = a && o;
            kk += a ? 1.0f : 0.0f;
        }
        it += 8;
        if (__ballot(a) == 0ull) break;       // all 64 rows fired
        if (cycseen) {                        // trajectory periodic ->
            kk += a ? (float)(MAX_ITERS - it) : 0.0f;  // survivors never fire
            break;
        }
    }

    kout[(size_t)row * NN + j] = kk;
}

// ---------------------------------------------------------------------------
// Norm kernel (r14/r18 verbatim, proven): blocks 0..255 -> ||k[i]||,
// 256..355 -> ||M[c]||. f64 accumulation; norms[row] = max(sqrt, 1e-8).
// ---------------------------------------------------------------------------
__global__ __launch_bounds__(256) void norm_kernel(
    const float* __restrict__ k, const float* __restrict__ M,
    float* __restrict__ norms)
{
    __shared__ double red[4];
    const int row = blockIdx.x;
    const float* src = (row < BB) ? (k + (size_t)row * NN)
                                  : (M + (size_t)(row - BB) * NN);
    double s = 0.0;
    for (int j = threadIdx.x * 4; j < NN; j += 1024) {
        const float4 v = *(const float4*)(src + j);
        s += (double)v.x * v.x + (double)v.y * v.y
           + (double)v.z * v.z + (double)v.w * v.w;
    }
    #pragma unroll
    for (int off = 32; off; off >>= 1) s += __shfl_down(s, off, 64);
    const int wid = threadIdx.x >> 6, lane = threadIdx.x & 63;
    if (lane == 0) red[wid] = s;
    __syncthreads();
    if (threadIdx.x == 0)
        norms[row] = fmaxf((float)sqrt(red[0] + red[1] + red[2] + red[3]), 1e-8f);
}

// ---------------------------------------------------------------------------
// Logits GEMM kernel (r18 verbatim, proven): block = 8 rows x 5 classes,
// grid 640; one ladder + one barrier; out = dot / (kn * Mn).
// ---------------------------------------------------------------------------
#define TR 8
#define TC 5
__global__ __launch_bounds__(256) void logits_gemm(
    const float* __restrict__ k, const float* __restrict__ M,
    const float* __restrict__ norms, float* __restrict__ out)
{
    __shared__ float red[4][TR][TC];

    const int rt  = blockIdx.x / (CC / TC);
    const int ct  = blockIdx.x % (CC / TC);
    const int r0  = rt * TR, c0 = ct * TC;
    const int tid = threadIdx.x;
    const int wid = tid >> 6, lane = tid & 63;

    float acc[TR][TC];
    #pragma unroll
    for (int r = 0; r < TR; ++r)
        #pragma unroll
        for (int c = 0; c < TC; ++c) acc[r][c] = 0.0f;

    for (int s = 0; s < 8; ++s) {
        const int jj = s * 1024 + tid * 4;
        float4 mv[TC];
        #pragma unroll
        for (int c = 0; c < TC; ++c)
            mv[c] = *(const float4*)(M + (size_t)(c0 + c) * NN + jj);
        #pragma unroll
        for (int r = 0; r < TR; ++r) {
            const float4 kv = *(const float4*)(k + (size_t)(r0 + r) * NN + jj);
            #pragma unroll
            for (int c = 0; c < TC; ++c)
                acc[r][c] += kv.x * mv[c].x + kv.y * mv[c].y
                           + kv.z * mv[c].z + kv.w * mv[c].w;
        }
    }

    #pragma unroll
    for (int off = 32; off; off >>= 1)
        #pragma unroll
        for (int r = 0; r < TR; ++r)
            #pragma unroll
            for (int c = 0; c < TC; ++c)
                acc[r][c] += __shfl_down(acc[r][c], off, 64);
    if (lane == 0)
        #pragma unroll
        for (int r = 0; r < TR; ++r)
            #pragma unroll
            for (int c = 0; c < TC; ++c)
                red[wid][r][c] = acc[r][c];
    __syncthreads();

    if (tid < TR * TC) {
        const int r = tid / TC, c = tid % TC;
        const float d = red[0][r][c] + red[1][r][c] + red[2][r][c] + red[3][r][c];
        out[(size_t)(r0 + r) * CC + (c0 + c)] =
            d / (norms[r0 + r] * norms[BB + c0 + c]);
    }
}

// ===========================================================================
// FALLBACK: round-10 fused kernel, verbatim (proven green), used only if
// ws_size is too small for the k matrix.
// ===========================================================================
__global__ __launch_bounds__(256) void gls_fused_kernel(
    const float* __restrict__ x, const float* __restrict__ bmap,
    const float* __restrict__ qini, const float* __restrict__ eps,
    const float* __restrict__ M, float* __restrict__ out)
{
    __shared__ float k_lds[NN];
    __shared__ double redsh[4];

    const int i   = blockIdx.x;
    const int tid = threadIdx.x;
    const int wid = tid >> 6, lane = tid & 63;

    double sumsq = 0.0;
    for (int s = 0; s < 32; ++s) {
        const int j = tid + 256 * s;
        const float bv = bmap[j];
        const float qv = qini[j];
        const float ev = eps[j];
        const float xv = x[(size_t)i * NN + j];
        const float lov = xv - ev;
        const float hiv = xv + ev;
        const float obv = 1.0f - bv;
        const float rb  = 1.0f / bv;
        const float rob = 1.0f / obv;

        float m  = qv;
        float kk = 1.0f;
        bool  a  = (qv != 0.0f);
        for (int it = 0; a && it < MAX_ITERS; ++it) {
            const bool  lt  = (m < bv);
            const float num = lt ? m  : (1.0f - m);
            const float r   = lt ? rb : rob;
            m = num * r;
            a = (m < lov) || (m > hiv);
            kk += a ? 1.0f : 0.0f;
        }
        k_lds[j] = kk;
        sumsq += (double)kk * (double)kk;
    }

    #pragma unroll
    for (int off = 32; off; off >>= 1) sumsq += __shfl_down(sumsq, off, 64);
    if (lane == 0) redsh[wid] = sumsq;
    __syncthreads();
    const double rn = fmax(sqrt(redsh[0] + redsh[1] + redsh[2] + redsh[3]), 1e-8);

    for (int cc2 = 0; cc2 < 25; ++cc2) {
        const int c = wid * 25 + cc2;
        const float4* Mp = (const float4*)(M + (size_t)c * NN);
        double dot = 0.0, msq = 0.0;
        #pragma unroll 4
        for (int s = 0; s < 32; ++s) {
            const float4 mv = Mp[lane + 64 * s];
            const float4 kv = *(const float4*)(&k_lds[4 * (lane + 64 * s)]);
            dot += (double)kv.x * (double)mv.x + (double)kv.y * (double)mv.y
                 + (double)kv.z * (double)mv.z + (double)kv.w * (double)mv.w;
            msq += (double)mv.x * (double)mv.x + (double)mv.y * (double)mv.y
                 + (double)mv.z * (double)mv.z + (double)mv.w * (double)mv.w;
        }
        #pragma unroll
        for (int off = 32; off; off >>= 1) {
            dot += __shfl_down(dot, off, 64);
            msq += __shfl_down(msq, off, 64);
        }
        if (lane == 0) {
            const double mn = fmax(sqrt(msq), 1e-8);
            out[(size_t)i * CC + c] = (float)(dot / (rn * mn));
        }
    }
}

// ---------------------------------------------------------------------------
extern "C" void kernel_launch(void* const* d_in, const int* in_sizes, int n_in,
                              void* d_out, int out_size, void* d_ws, size_t ws_size,
                              hipStream_t stream) {
    const float* x = (const float*)d_in[0];  // (256, 8192)
    const float* b = (const float*)d_in[1];  // (8192,)
    const float* q = (const float*)d_in[2];  // (8192,)
    const float* e = (const float*)d_in[3];  // (8192,)
    const float* M = (const float*)d_in[4];  // (100, 8192)
    float* out = (float*)d_out;              // (256, 100)

    // ws layout: kbuf | norms[356]
    const size_t need = (size_t)BB * NN * sizeof(float) + (BB + CC) * sizeof(float);
    if (ws_size >= need) {
        float* kbuf  = (float*)d_ws;
        float* norms = kbuf + (size_t)BB * NN;
        fire_kernel<<<dim3(NN), dim3(256), 0, stream>>>(x, b, q, e, kbuf);
        norm_kernel<<<dim3(BB + CC), dim3(256), 0, stream>>>(kbuf, M, norms);
        logits_gemm<<<dim3((BB / TR) * (CC / TC)), dim3(256), 0, stream>>>(kbuf, M, norms, out);
    } else {
        gls_fused_kernel<<<dim3(BB), dim3(256), 0, stream>>>(x, b, q, e, M, out);
    }
}